// Round 1
// baseline (566.323 us; speedup 1.0000x reference)
//
#include <hip/hip_runtime.h>
#include <hip/hip_bf16.h>
#include <math.h>

// Problem constants (hard-coded per reference: D=300, TOPK=20, setup N=2,T=4096,h=6)
#define T      4096
#define Dm     300
#define NH     6
#define DH     50
#define NB     2
#define NBATCH 12   // NH*NB
#define KTOP   20

// ---------------------------------------------------------------------------
// Kernel 1: projection  Yt[b][j][t] = sum_i X[n][t][i] * W[head*DH+j][i]
// X: [NB][T][Dm] row-major, W: [Dm][Dm] (out,in) row-major
// Yt: [NBATCH][DH][T]  (b = head*NB + n)  -- transposed for the score GEMM
// GEMM: M=8192 rows (n,t), N=300 cols (j), K=300. Tile 128x64, BK=20, 8x4 micro.
// ---------------------------------------------------------------------------
__global__ __launch_bounds__(256) void proj_kernel(
    const float* __restrict__ X, const float* __restrict__ W,
    float* __restrict__ Yt)
{
    __shared__ float Xs[20][132];   // padded stride: breaks pow2 bank aliasing
    __shared__ float Ws[20][68];

    const int row0 = blockIdx.x * 128;   // 0..8064 (tiles never straddle n)
    const int j0   = blockIdx.y * 64;    // 0,64,128,192,256 (last tile guarded)
    const int tid  = threadIdx.x;
    const int tx   = tid & 15;           // j group
    const int ty   = tid >> 4;           // t group

    float acc[8][4];
#pragma unroll
    for (int r = 0; r < 8; ++r)
#pragma unroll
        for (int c = 0; c < 4; ++c) acc[r][c] = 0.f;

    for (int k0 = 0; k0 < 300; k0 += 20) {
        // stage X chunk 128x20 (coalesced-ish 80B row segments)
#pragma unroll
        for (int l = 0; l < 10; ++l) {
            int idx = l * 256 + tid;            // 0..2559
            int m = idx / 20, k = idx % 20;
            Xs[k][m] = X[(row0 + m) * 300 + k0 + k];
        }
        // stage W chunk 64x20 (guard j<300 -> 0)
#pragma unroll
        for (int l = 0; l < 5; ++l) {
            int idx = l * 256 + tid;            // 0..1279
            int nn = idx / 20, k = idx % 20;
            int j = j0 + nn;
            Ws[k][nn] = (j < 300) ? W[j * 300 + k0 + k] : 0.f;
        }
        __syncthreads();
#pragma unroll
        for (int kk = 0; kk < 20; ++kk) {
            float4 xa = *(const float4*)&Xs[kk][ty * 8];
            float4 xb = *(const float4*)&Xs[kk][ty * 8 + 4];
            float4 wv = *(const float4*)&Ws[kk][tx * 4];
            float xr[8] = {xa.x, xa.y, xa.z, xa.w, xb.x, xb.y, xb.z, xb.w};
            float wc[4] = {wv.x, wv.y, wv.z, wv.w};
#pragma unroll
            for (int r = 0; r < 8; ++r)
#pragma unroll
                for (int c = 0; c < 4; ++c)
                    acc[r][c] += xr[r] * wc[c];
        }
        __syncthreads();
    }

    const int n  = row0 / T;
    const int t0 = row0 % T;
#pragma unroll
    for (int c = 0; c < 4; ++c) {
        int j = j0 + tx * 4 + c;
        if (j < 300) {
            int head = j / DH, jcol = j % DH;
            float* dst = Yt + (size_t)((head * NB + n) * DH + jcol) * T + t0 + ty * 8;
            *(float4*)dst       = make_float4(acc[0][c], acc[1][c], acc[2][c], acc[3][c]);
            *(float4*)(dst + 4) = make_float4(acc[4][c], acc[5][c], acc[6][c], acc[7][c]);
        }
    }
}

// ---------------------------------------------------------------------------
// Kernel 2: scores + column max.
// For batch b, column block of 128 keys: iterate all 32 query tiles of 128,
// S = Q(128x50) * K^T, track running max over queries per key column.
// maxatt[b][k] = max_q(Q_q . K_k) * (1/sqrt(50))
// ---------------------------------------------------------------------------
__global__ __launch_bounds__(256) void score_colmax_kernel(
    const float* __restrict__ Qt, const float* __restrict__ Kt,
    float* __restrict__ maxatt)
{
    __shared__ float Klds[50][132];
    __shared__ float Qlds[50][132];

    const int k0  = blockIdx.x * 128;   // key-column block
    const int b   = blockIdx.y;         // 0..11
    const int tid = threadIdx.x;
    const int tx  = tid & 15, ty = tid >> 4;

    // stage K tile once (stays resident)
    for (int i = tid; i < 50 * 32; i += 256) {
        int d = i >> 5, c4 = i & 31;
        *(float4*)&Klds[d][c4 * 4] =
            *(const float4*)(Kt + (size_t)(b * DH + d) * T + k0 + c4 * 4);
    }

    float cmax[8];
#pragma unroll
    for (int c = 0; c < 8; ++c) cmax[c] = -INFINITY;

    for (int qt = 0; qt < 32; ++qt) {
        int q0 = qt * 128;
        __syncthreads();   // protects Qlds reuse; first iter also covers Klds staging
        for (int i = tid; i < 50 * 32; i += 256) {
            int d = i >> 5, c4 = i & 31;
            *(float4*)&Qlds[d][c4 * 4] =
                *(const float4*)(Qt + (size_t)(b * DH + d) * T + q0 + c4 * 4);
        }
        __syncthreads();

        float acc[8][8];
#pragma unroll
        for (int r = 0; r < 8; ++r)
#pragma unroll
            for (int c = 0; c < 8; ++c) acc[r][c] = 0.f;

        for (int kk = 0; kk < 50; ++kk) {
            float4 qa = *(const float4*)&Qlds[kk][ty * 4];
            float4 qb = *(const float4*)&Qlds[kk][ty * 4 + 64];
            float4 ka = *(const float4*)&Klds[kk][tx * 4];
            float4 kb = *(const float4*)&Klds[kk][tx * 4 + 64];
            float qr[8] = {qa.x, qa.y, qa.z, qa.w, qb.x, qb.y, qb.z, qb.w};
            float kc[8] = {ka.x, ka.y, ka.z, ka.w, kb.x, kb.y, kb.z, kb.w};
#pragma unroll
            for (int r = 0; r < 8; ++r)
#pragma unroll
                for (int c = 0; c < 8; ++c)
                    acc[r][c] += qr[r] * kc[c];
        }
#pragma unroll
        for (int c = 0; c < 8; ++c)
#pragma unroll
            for (int r = 0; r < 8; ++r)
                cmax[c] = fmaxf(cmax[c], acc[r][c]);
    }

    // reduce cmax over the 16 ty-groups; reuse Qlds as scratch [16][128]
    __syncthreads();
    float* red = &Qlds[0][0];
#pragma unroll
    for (int c = 0; c < 8; ++c) {
        int col = (c < 4) ? (tx * 4 + c) : (tx * 4 + 64 + (c - 4));
        red[ty * 128 + col] = cmax[c];
    }
    __syncthreads();
    if (tid < 128) {
        float m = red[tid];
#pragma unroll
        for (int y = 1; y < 16; ++y) m = fmaxf(m, red[y * 128 + tid]);
        maxatt[b * T + k0 + tid] = m * 0.14142135623730951f;  // * 1/sqrt(50)
    }
}

// ---------------------------------------------------------------------------
// Kernel 3: per batch b: top-20 of maxatt[b][:], softmax, gather K rows,
// write out[n][0][head*50+j].
// ---------------------------------------------------------------------------
__global__ __launch_bounds__(256) void topk_kernel(
    const float* __restrict__ maxatt, const float* __restrict__ Kt,
    float* __restrict__ out)
{
    __shared__ float vals[T];
    __shared__ float redv[256];
    __shared__ int   redi[256];
    __shared__ float selval[KTOP];
    __shared__ int   selidx[KTOP];
    __shared__ float probs[KTOP];

    const int b   = blockIdx.x;
    const int tid = threadIdx.x;

    for (int i = tid; i < T; i += 256) vals[i] = maxatt[b * T + i];
    __syncthreads();

    for (int l = 0; l < KTOP; ++l) {
        float bv = -INFINITY; int bi = 0x7fffffff;
        for (int i = tid; i < T; i += 256) {
            float v = vals[i];
            if (v > bv) { bv = v; bi = i; }   // ascending i: strict > keeps lowest idx
        }
        redv[tid] = bv; redi[tid] = bi;
        __syncthreads();
        for (int s = 128; s > 0; s >>= 1) {
            if (tid < s) {
                float v2 = redv[tid + s]; int i2 = redi[tid + s];
                if (v2 > redv[tid] || (v2 == redv[tid] && i2 < redi[tid])) {
                    redv[tid] = v2; redi[tid] = i2;
                }
            }
            __syncthreads();
        }
        if (tid == 0) {
            selval[l] = redv[0]; selidx[l] = redi[0];
            vals[redi[0]] = -INFINITY;
        }
        __syncthreads();
    }

    if (tid == 0) {
        float m = selval[0];   // first selection is the global max
        float s = 0.f;
        for (int l = 0; l < KTOP; ++l) { float e = expf(selval[l] - m); probs[l] = e; s += e; }
        float inv = 1.f / s;
        for (int l = 0; l < KTOP; ++l) probs[l] *= inv;
    }
    __syncthreads();

    if (tid < DH) {
        float acc = 0.f;
#pragma unroll
        for (int l = 0; l < KTOP; ++l)
            acc += probs[l] * Kt[(size_t)(b * DH + tid) * T + selidx[l]];
        int head = b / NB, n = b % NB;
        out[n * Dm + head * DH + tid] = acc;
    }
}

// ---------------------------------------------------------------------------
extern "C" void kernel_launch(void* const* d_in, const int* in_sizes, int n_in,
                              void* d_out, int out_size, void* d_ws, size_t ws_size,
                              hipStream_t stream) {
    const float* querys = (const float*)d_in[0];
    const float* keys   = (const float*)d_in[1];
    // d_in[2] values: unused by the reference's output
    const float* Wq     = (const float*)d_in[3];
    const float* Wk     = (const float*)d_in[4];
    // d_in[5] Wv, d_in[6] num_heads: unused / hard-coded

    float* out = (float*)d_out;
    float* ws  = (float*)d_ws;

    float* Qt     = ws;                                  // [12][50][4096]
    float* Kt     = Qt + (size_t)NBATCH * DH * T;        // [12][50][4096]
    float* maxatt = Kt + (size_t)NBATCH * DH * T;        // [12][4096]
    // total ws use: ~19.9 MB

    proj_kernel<<<dim3(64, 5), 256, 0, stream>>>(querys, Wq, Qt);
    proj_kernel<<<dim3(64, 5), 256, 0, stream>>>(keys,   Wk, Kt);
    score_colmax_kernel<<<dim3(32, NBATCH), 256, 0, stream>>>(Qt, Kt, maxatt);
    topk_kernel<<<NBATCH, 256, 0, stream>>>(maxatt, Kt, out);
}

// Round 2
// 486.278 us; speedup vs baseline: 1.1646x; 1.1646x over previous
//
#include <hip/hip_runtime.h>
#include <hip/hip_bf16.h>
#include <math.h>

// Problem constants (hard-coded per reference: D=300, TOPK=20, setup N=2,T=4096,h=6)
#define T      4096
#define Dm     300
#define NH     6
#define DH     50
#define NB     2
#define NBATCH 12   // NH*NB
#define KTOP   20
#define QCHUNK 4    // score kernel: query-loop split factor (grid.z)

// ---------------------------------------------------------------------------
// Kernel 1: projection  Yt[b][j][t] = sum_i X[n][t][i] * W[head*DH+j][i]
// X: [NB][T][Dm] row-major, W: [Dm][Dm] (out,in) row-major
// Yt: [NBATCH][DH][T]  (b = head*NB + n)  -- transposed for the score GEMM
// GEMM: M=8192 rows (n,t), N=300 cols (j), K=300. Tile 128x64, BK=20, 8x4 micro.
// blockIdx.z selects (querys,Wq,Qt) vs (keys,Wk,Kt) so both run in one launch.
// ---------------------------------------------------------------------------
__global__ __launch_bounds__(256) void proj_kernel(
    const float* __restrict__ Xq, const float* __restrict__ Wq_,
    const float* __restrict__ Xk, const float* __restrict__ Wk_,
    float* __restrict__ Qt, float* __restrict__ Kt)
{
    __shared__ float Xs[20][132];   // padded stride: breaks pow2 bank aliasing
    __shared__ float Ws[20][68];

    const float* X  = blockIdx.z ? Xk : Xq;
    const float* W  = blockIdx.z ? Wk_ : Wq_;
    float*       Yt = blockIdx.z ? Kt : Qt;

    const int row0 = blockIdx.x * 128;   // 0..8064 (tiles never straddle n)
    const int j0   = blockIdx.y * 64;    // 0,64,128,192,256 (last tile guarded)
    const int tid  = threadIdx.x;
    const int tx   = tid & 15;           // j group
    const int ty   = tid >> 4;           // t group

    float acc[8][4];
#pragma unroll
    for (int r = 0; r < 8; ++r)
#pragma unroll
        for (int c = 0; c < 4; ++c) acc[r][c] = 0.f;

    for (int k0 = 0; k0 < 300; k0 += 20) {
        // stage X chunk 128x20
#pragma unroll
        for (int l = 0; l < 10; ++l) {
            int idx = l * 256 + tid;            // 0..2559
            int m = idx / 20, k = idx % 20;
            Xs[k][m] = X[(row0 + m) * 300 + k0 + k];
        }
        // stage W chunk 64x20 (guard j<300 -> 0)
#pragma unroll
        for (int l = 0; l < 5; ++l) {
            int idx = l * 256 + tid;            // 0..1279
            int nn = idx / 20, k = idx % 20;
            int j = j0 + nn;
            Ws[k][nn] = (j < 300) ? W[j * 300 + k0 + k] : 0.f;
        }
        __syncthreads();
#pragma unroll
        for (int kk = 0; kk < 20; ++kk) {
            float4 xa = *(const float4*)&Xs[kk][ty * 8];
            float4 xb = *(const float4*)&Xs[kk][ty * 8 + 4];
            float4 wv = *(const float4*)&Ws[kk][tx * 4];
            float xr[8] = {xa.x, xa.y, xa.z, xa.w, xb.x, xb.y, xb.z, xb.w};
            float wc[4] = {wv.x, wv.y, wv.z, wv.w};
#pragma unroll
            for (int r = 0; r < 8; ++r)
#pragma unroll
                for (int c = 0; c < 4; ++c)
                    acc[r][c] += xr[r] * wc[c];
        }
        __syncthreads();
    }

    const int n  = row0 / T;
    const int t0 = row0 % T;
#pragma unroll
    for (int c = 0; c < 4; ++c) {
        int j = j0 + tx * 4 + c;
        if (j < 300) {
            int head = j / DH, jcol = j % DH;
            float* dst = Yt + (size_t)((head * NB + n) * DH + jcol) * T + t0 + ty * 8;
            *(float4*)dst       = make_float4(acc[0][c], acc[1][c], acc[2][c], acc[3][c]);
            *(float4*)(dst + 4) = make_float4(acc[4][c], acc[5][c], acc[6][c], acc[7][c]);
        }
    }
}

// ---------------------------------------------------------------------------
// Kernel 2: scores + partial column max over a chunk of query tiles.
// grid = (32 k-blocks, 12 batches, QCHUNK q-chunks); each block: K tile (128)
// resident in LDS, loop 32/QCHUNK query tiles of 128, 8x8 register microtile,
// running per-column max. pmax[(chunk*NBATCH + b)*T + k] = partial max (unscaled).
// ---------------------------------------------------------------------------
__global__ __launch_bounds__(256) void score_colmax_kernel(
    const float* __restrict__ Qt, const float* __restrict__ Kt,
    float* __restrict__ pmax)
{
    __shared__ float Klds[50][132];
    __shared__ float Qlds[50][132];

    const int k0    = blockIdx.x * 128;   // key-column block
    const int b     = blockIdx.y;         // 0..11
    const int chunk = blockIdx.z;         // 0..QCHUNK-1
    const int tid   = threadIdx.x;
    const int tx    = tid & 15, ty = tid >> 4;

    // stage K tile once (stays resident)
    for (int i = tid; i < 50 * 32; i += 256) {
        int d = i >> 5, c4 = i & 31;
        *(float4*)&Klds[d][c4 * 4] =
            *(const float4*)(Kt + (size_t)(b * DH + d) * T + k0 + c4 * 4);
    }

    float cmax[8];
#pragma unroll
    for (int c = 0; c < 8; ++c) cmax[c] = -INFINITY;

    const int qt_beg = chunk * (32 / QCHUNK);
    const int qt_end = qt_beg + (32 / QCHUNK);
    for (int qt = qt_beg; qt < qt_end; ++qt) {
        int q0 = qt * 128;
        __syncthreads();   // protects Qlds reuse; first iter also covers Klds staging
        for (int i = tid; i < 50 * 32; i += 256) {
            int d = i >> 5, c4 = i & 31;
            *(float4*)&Qlds[d][c4 * 4] =
                *(const float4*)(Qt + (size_t)(b * DH + d) * T + q0 + c4 * 4);
        }
        __syncthreads();

        float acc[8][8];
#pragma unroll
        for (int r = 0; r < 8; ++r)
#pragma unroll
            for (int c = 0; c < 8; ++c) acc[r][c] = 0.f;

        for (int kk = 0; kk < 50; ++kk) {
            float4 qa = *(const float4*)&Qlds[kk][ty * 4];
            float4 qb = *(const float4*)&Qlds[kk][ty * 4 + 64];
            float4 ka = *(const float4*)&Klds[kk][tx * 4];
            float4 kb = *(const float4*)&Klds[kk][tx * 4 + 64];
            float qr[8] = {qa.x, qa.y, qa.z, qa.w, qb.x, qb.y, qb.z, qb.w};
            float kc[8] = {ka.x, ka.y, ka.z, ka.w, kb.x, kb.y, kb.z, kb.w};
#pragma unroll
            for (int r = 0; r < 8; ++r)
#pragma unroll
                for (int c = 0; c < 8; ++c)
                    acc[r][c] += qr[r] * kc[c];
        }
#pragma unroll
        for (int c = 0; c < 8; ++c)
#pragma unroll
            for (int r = 0; r < 8; ++r)
                cmax[c] = fmaxf(cmax[c], acc[r][c]);
    }

    // reduce cmax over the 16 ty-groups; reuse Qlds as scratch [16][128]
    __syncthreads();
    float* red = &Qlds[0][0];
#pragma unroll
    for (int c = 0; c < 8; ++c) {
        int col = (c < 4) ? (tx * 4 + c) : (tx * 4 + 64 + (c - 4));
        red[ty * 128 + col] = cmax[c];
    }
    __syncthreads();
    if (tid < 128) {
        float m = red[tid];
#pragma unroll
        for (int y = 1; y < 16; ++y) m = fmaxf(m, red[y * 128 + tid]);
        pmax[(size_t)(chunk * NBATCH + b) * T + k0 + tid] = m;  // unscaled partial
    }
}

// ---------------------------------------------------------------------------
// Kernel 3: per batch b: reduce pmax chunks + scale, top-20 (cached-argmax +
// shuffle reduce), softmax, gather K rows, write out[n][0][head*50+j].
// ---------------------------------------------------------------------------
__global__ __launch_bounds__(256) void topk_kernel(
    const float* __restrict__ pmax, const float* __restrict__ Kt,
    float* __restrict__ out)
{
    __shared__ float vals[T];
    __shared__ float wredv[4];
    __shared__ int   wredi[4];
    __shared__ float selval[KTOP];
    __shared__ int   selidx[KTOP];
    __shared__ float probs[KTOP];

    const int b    = blockIdx.x;
    const int tid  = threadIdx.x;
    const int lane = tid & 63;
    const int wv_  = tid >> 6;

    // chunk-reduce + scale; track per-thread argmax over owned (strided) slots
    float bv = -INFINITY; int bi = 0x7fffffff;
    for (int i = tid; i < T; i += 256) {
        float m = pmax[(size_t)b * T + i];
#pragma unroll
        for (int c = 1; c < QCHUNK; ++c)
            m = fmaxf(m, pmax[(size_t)(c * NBATCH + b) * T + i]);
        m *= 0.14142135623730951f;   // 1/sqrt(50)
        vals[i] = m;
        if (m > bv) { bv = m; bi = i; }   // ascending i: strict > keeps lowest idx
    }
    __syncthreads();

    for (int l = 0; l < KTOP; ++l) {
        // 64-lane shuffle argmax (lowest-index tie-break)
        float v = bv; int i = bi;
#pragma unroll
        for (int off = 32; off > 0; off >>= 1) {
            float v2 = __shfl_down(v, off);
            int   i2 = __shfl_down(i, off);
            if (v2 > v || (v2 == v && i2 < i)) { v = v2; i = i2; }
        }
        if (lane == 0) { wredv[wv_] = v; wredi[wv_] = i; }
        __syncthreads();
        float sv = wredv[0]; int si = wredi[0];
#pragma unroll
        for (int w = 1; w < 4; ++w) {
            float v2 = wredv[w]; int i2 = wredi[w];
            if (v2 > sv || (v2 == sv && i2 < si)) { sv = v2; si = i2; }
        }
        if (tid == 0) { selval[l] = sv; selidx[l] = si; }
        // only the owning thread's local max changes; it rescans its 16 slots
        if (tid == (si & 255)) {
            vals[si] = -INFINITY;
            bv = -INFINITY; bi = 0x7fffffff;
            for (int i2 = tid; i2 < T; i2 += 256) {
                float m = vals[i2];
                if (m > bv) { bv = m; bi = i2; }
            }
        }
        __syncthreads();   // wredv reuse + selval visibility
    }

    if (tid == 0) {
        float m = selval[0];   // first selection is the global max
        float s = 0.f;
        for (int l = 0; l < KTOP; ++l) { float e = expf(selval[l] - m); probs[l] = e; s += e; }
        float inv = 1.f / s;
        for (int l = 0; l < KTOP; ++l) probs[l] *= inv;
    }
    __syncthreads();

    if (tid < DH) {
        float acc = 0.f;
#pragma unroll
        for (int l = 0; l < KTOP; ++l)
            acc += probs[l] * Kt[(size_t)(b * DH + tid) * T + selidx[l]];
        int head = b / NB, n = b % NB;
        out[n * Dm + head * DH + tid] = acc;
    }
}

// ---------------------------------------------------------------------------
extern "C" void kernel_launch(void* const* d_in, const int* in_sizes, int n_in,
                              void* d_out, int out_size, void* d_ws, size_t ws_size,
                              hipStream_t stream) {
    const float* querys = (const float*)d_in[0];
    const float* keys   = (const float*)d_in[1];
    // d_in[2] values: unused by the reference's output
    const float* Wq     = (const float*)d_in[3];
    const float* Wk     = (const float*)d_in[4];
    // d_in[5] Wv, d_in[6] num_heads: unused / hard-coded

    float* out = (float*)d_out;
    float* ws  = (float*)d_ws;

    float* Qt   = ws;                                  // [12][50][4096]
    float* Kt   = Qt + (size_t)NBATCH * DH * T;        // [12][50][4096]
    float* pmax = Kt + (size_t)NBATCH * DH * T;        // [QCHUNK][12][4096]
    // total ws use: 19.66 MB + 0.79 MB = 20.45 MB

    proj_kernel<<<dim3(64, 5, 2), 256, 0, stream>>>(querys, Wq, keys, Wk, Qt, Kt);
    score_colmax_kernel<<<dim3(32, NBATCH, QCHUNK), 256, 0, stream>>>(Qt, Kt, pmax);
    topk_kernel<<<NBATCH, 256, 0, stream>>>(pmax, Kt, out);
}